// Round 19
// baseline (50.145 us; speedup 1.0000x reference)
//
#include <hip/hip_runtime.h>
#include <hip/hip_bf16.h>

#define N 8192
#define D 128
#define NG 64                // 128-row/col tile groups
#define NSTRIP 544           // sum_r ceil((64-r)/4)
#define NLBL 100             // labels in [0,100)
#define LCHK 8               // labelsum chunks (1024 rows each)

#define K1F 14.426950408889634f    // 10 * log2(e)
#define K0F (-14.426950408889634f)

#if __has_builtin(__builtin_amdgcn_exp2f)
#define EXP2(x) __builtin_amdgcn_exp2f(x)
#else
#define EXP2(x) exp2f(x)
#endif

typedef __attribute__((ext_vector_type(8))) short bf16x8;
typedef __attribute__((ext_vector_type(4))) float f32x4;
typedef __attribute__((address_space(1))) const unsigned int gu32;
typedef __attribute__((address_space(3))) unsigned int lu32;

// ---------------- K1: row-normalize z -> bf16 zn, plus self-dot d_ii --------
__global__ __launch_bounds__(256) void znorm_kernel(const float* __restrict__ z,
                                                    ushort* __restrict__ zn,
                                                    float* __restrict__ dii) {
    const int wid  = threadIdx.x >> 6;
    const int lane = threadIdx.x & 63;
    const int row  = blockIdx.x * 4 + wid;       // grid = N/4 blocks
    const float2 v = reinterpret_cast<const float2*>(z + (size_t)row * D)[lane];
    float ss = v.x * v.x + v.y * v.y;
    #pragma unroll
    for (int m = 1; m < 64; m <<= 1) ss += __shfl_xor(ss, m);
    const float inv = 1.0f / fmaxf(sqrtf(ss), 1e-8f);
    __hip_bfloat16 b0 = __float2bfloat16(v.x * inv);
    __hip_bfloat16 b1 = __float2bfloat16(v.y * inv);
    ushort2 o;
    o.x = *reinterpret_cast<ushort*>(&b0);
    o.y = *reinterpret_cast<ushort*>(&b1);
    reinterpret_cast<ushort2*>(zn + (size_t)row * D)[lane] = o;
    const float f0 = __bfloat162float(b0), f1 = __bfloat162float(b1);
    float s2 = f0 * f0 + f1 * f1;
    #pragma unroll
    for (int m = 1; m < 64; m <<= 1) s2 += __shfl_xor(s2, m);
    if (lane == 0) dii[row] = s2;
}

// ---------------- K2: labelsum via deterministic match-compaction ------------
__global__ __launch_bounds__(256) void labelsum_kernel(const ushort* __restrict__ zn,
                                                       const int* __restrict__ y,
                                                       float* __restrict__ tpart,
                                                       int* __restrict__ cpart) {
    __shared__ int idxs[1024];
    __shared__ int sc[256];
    const int c = blockIdx.x / LCHK;
    const int k = blockIdx.x % LCHK;
    const int t = threadIdx.x;
    const int base = k * 1024;

    int ys0 = y[base + t * 4 + 0], ys1 = y[base + t * 4 + 1];
    int ys2 = y[base + t * 4 + 2], ys3 = y[base + t * 4 + 3];
    const int m0 = (ys0 == c), m1 = (ys1 == c), m2 = (ys2 == c), m3 = (ys3 == c);
    const int myCnt = m0 + m1 + m2 + m3;
    sc[t] = myCnt;
    __syncthreads();
    #pragma unroll
    for (int off = 1; off < 256; off <<= 1) {
        const int v = sc[t];
        const int add = (t >= off) ? sc[t - off] : 0;
        __syncthreads();
        sc[t] = v + add;
        __syncthreads();
    }
    const int total = sc[255];
    int pos = sc[t] - myCnt;                      // exclusive prefix
    if (m0) idxs[pos++] = t * 4 + 0;
    if (m1) idxs[pos++] = t * 4 + 1;
    if (m2) idxs[pos++] = t * 4 + 2;
    if (m3) idxs[pos++] = t * 4 + 3;
    __syncthreads();

    if (t == 0) cpart[k * NLBL + c] = total;      // exact count, no atomics
    if (t < D) {
        float acc = 0.0f;
        int i = 0;
        for (; i + 4 <= total; i += 4) {          // batch 4: independent loads
            const int r0 = idxs[i], r1 = idxs[i + 1], r2 = idxs[i + 2], r3 = idxs[i + 3];
            __hip_bfloat16 h0, h1, h2, h3;
            *reinterpret_cast<ushort*>(&h0) = zn[(size_t)(base + r0) * D + t];
            *reinterpret_cast<ushort*>(&h1) = zn[(size_t)(base + r1) * D + t];
            *reinterpret_cast<ushort*>(&h2) = zn[(size_t)(base + r2) * D + t];
            *reinterpret_cast<ushort*>(&h3) = zn[(size_t)(base + r3) * D + t];
            acc += __bfloat162float(h0);
            acc += __bfloat162float(h1);
            acc += __bfloat162float(h2);
            acc += __bfloat162float(h3);
        }
        for (; i < total; ++i) {
            __hip_bfloat16 hb;
            *reinterpret_cast<ushort*>(&hb) = zn[(size_t)(base + idxs[i]) * D + t];
            acc += __bfloat162float(hb);
        }
        tpart[((size_t)k * NLBL + c) * D + t] = acc;
    }
}

// ---------------- K3: STRIP-4 upper-triangle tiles --------------------------
// Block = strip (r, c0..c0+L-1), L<=4: A-frags loaded ONCE, B double-buffered
// (fragment-order LDS, conflict-free; stage(t+1) issues before compute(t) so
// L2 latency hides under ~1240 cyc of MFMA). Per-wave compute per block is
// 4x R18's (256 vs 64 MFMA) against the same ~1500-cyc prologue -> per-block
// efficiency ~45% -> ~77%. Col-sums deferred in registers (zAll, statically
// indexed). Slot bookkeeping: accumulated row-partial -> slot c0; explicit
// zeros -> slots c0+1..c0+L-1; col-side per tile -> slot r of group c. Every
// P[slot][i] written exactly once -> deterministic, no atomics.
__global__ __launch_bounds__(256, 2) void supcon_main(const ushort* __restrict__ zn,
                                                      float* __restrict__ P) {
    __shared__ ushort Bsm[2][32 * 64 * 8];   // 2 x 32 KB, [jt*4+s][lane] 16B entries
    __shared__ float  zcLDS[4][128];         // 2 KB
    const int wid  = threadIdx.x >> 6;
    const int lane = threadIdx.x & 63;
    const int g    = lane >> 4;
    const int lj   = lane & 15;

    // decode strip -> (r, c0, L): row r has 16-(r>>2) strips, strip j at r+4j
    int b = blockIdx.x;
    int r = 0;
    while (b >= 16 - (r >> 2)) { b -= 16 - (r >> 2); ++r; }
    const int c0 = r + b * 4;
    const int L  = (64 - c0 < 4) ? (64 - c0) : 4;

    const int rowBase = r * 128 + wid * 32;

    // stage tile column-group cc into Bsm[buf] (8 glds x 1 KB per wave)
    auto STAGE = [&](int buf, int cc) {
        const size_t colBase = (size_t)cc * 128;
        #pragma unroll
        for (int q = 0; q < 8; ++q) {
            const int jt = wid * 2 + (q >> 2);
            const int s  = q & 3;
            const ushort* src = zn + (colBase + jt * 16 + lj) * D + s * 32 + g * 8;
            __builtin_amdgcn_global_load_lds((gu32*)src,
                (lu32*)&Bsm[buf][(jt * 4 + s) * 64 * 8], 16, 0, 0);
        }
    };

    STAGE(0, c0);        // prologue stage; latency overlaps A-loads below

    // A fragments: 2 M-tiles x 4 K-steps (32 VGPR), loaded once per strip
    bf16x8 a[2][4];
    #pragma unroll
    for (int m = 0; m < 2; ++m) {
        const ushort* rp = zn + (size_t)(rowBase + m * 16 + lj) * D;
        #pragma unroll
        for (int s = 0; s < 4; ++s)
            a[m][s] = *reinterpret_cast<const bf16x8*>(rp + s * 32 + g * 8);
    }

    float Zrow[2][4];
    #pragma unroll
    for (int m = 0; m < 2; ++m)
        #pragma unroll
        for (int rr = 0; rr < 4; ++rr) Zrow[m][rr] = 0.0f;
    float zAll[4][8];    // per-tile col partials; ALL indices compile-time

    asm volatile("s_waitcnt vmcnt(0)");
    __syncthreads();

    const f32x4 zero4 = {0.f, 0.f, 0.f, 0.f};
    int buf = 0;
    #pragma unroll
    for (int t = 0; t < 4; ++t) {
        if (t < L) {                              // block-uniform guard
            if (t + 1 < L) STAGE(buf ^ 1, c0 + t + 1);   // async under compute
            #pragma unroll
            for (int jt = 0; jt < 8; ++jt) {
                bf16x8 bb[4];
                #pragma unroll
                for (int s = 0; s < 4; ++s)
                    bb[s] = *reinterpret_cast<const bf16x8*>(
                        &Bsm[buf][((jt * 4 + s) * 64 + lane) * 8]);  // lane-linear
                f32x4 acc[2] = {zero4, zero4};
                #pragma unroll
                for (int s = 0; s < 4; ++s)
                    #pragma unroll
                    for (int m = 0; m < 2; ++m)
                        acc[m] = __builtin_amdgcn_mfma_f32_16x16x32_bf16(a[m][s], bb[s], acc[m], 0, 0, 0);
                float esum = 0.0f;
                #pragma unroll
                for (int m = 0; m < 2; ++m)
                    #pragma unroll
                    for (int rr = 0; rr < 4; ++rr) {
                        const float e = EXP2(fmaf(acc[m][rr], K1F, K0F)); // exp(10*dot-10)
                        Zrow[m][rr] += e;
                        esum += e;
                    }
                zAll[t][jt] = esum;
            }
            asm volatile("s_waitcnt vmcnt(0)");
            __syncthreads();
            buf ^= 1;
        }
    }

    // row side: reduce accumulated Zrow over 16 cols -> P[c0][rows of r]
    #pragma unroll
    for (int m = 0; m < 2; ++m)
        #pragma unroll
        for (int rr = 0; rr < 4; ++rr)
            #pragma unroll
            for (int mk = 1; mk < 16; mk <<= 1)
                Zrow[m][rr] += __shfl_xor(Zrow[m][rr], mk);
    if (lj == 0) {
        #pragma unroll
        for (int m = 0; m < 2; ++m)
            #pragma unroll
            for (int rr = 0; rr < 4; ++rr)
                P[(size_t)c0 * N + rowBase + m * 16 + g * 4 + rr] = Zrow[m][rr];
    }
    // zero the strip's other row-side slots (exactly-once coverage)
    #pragma unroll
    for (int k = 1; k < 4; ++k)
        if (k < L && threadIdx.x < 128)
            P[(size_t)(c0 + k) * N + r * 128 + threadIdx.x] = 0.0f;

    // col side per tile (skip diagonal): reduce over g -> P[r][cols of c0+t]
    #pragma unroll
    for (int t = 0; t < 4; ++t) {
        const bool doCol = (t < L) && (c0 + t != r);   // block-uniform
        if (doCol) {
            float zc[8];
            #pragma unroll
            for (int jt = 0; jt < 8; ++jt) {
                float v = zAll[t][jt];
                v += __shfl_xor(v, 16);
                v += __shfl_xor(v, 32);
                zc[jt] = v;
            }
            if (lane < 16) {
                #pragma unroll
                for (int jt = 0; jt < 8; ++jt)
                    zcLDS[wid][jt * 16 + lane] = zc[jt];
            }
            __syncthreads();
            if (threadIdx.x < 128) {
                const float s = zcLDS[0][threadIdx.x] + zcLDS[1][threadIdx.x] +
                                zcLDS[2][threadIdx.x] + zcLDS[3][threadIdx.x];
                P[(size_t)r * N + (size_t)(c0 + t) * 128 + threadIdx.x] = s;
            }
            __syncthreads();
        }
    }
}

// ---------------- K4: finalize (t- and cnt-reductions folded in) ------------
__global__ __launch_bounds__(256) void supcon_finalize(const ushort* __restrict__ zn,
                                                       const int* __restrict__ y,
                                                       const float* __restrict__ P,
                                                       const float* __restrict__ dii,
                                                       const float* __restrict__ tpart,
                                                       const int* __restrict__ cpart,
                                                       float* __restrict__ out) {
    const int wid  = threadIdx.x >> 6;
    const int lane = threadIdx.x & 63;
    const int row  = blockIdx.x * 4 + wid;
    const int c    = y[row];
    const ushort2 u = reinterpret_cast<const ushort2*>(zn + (size_t)row * D)[lane];
    // on-the-fly t[c] = sum_k tpart[k][c][:]; lane owns dims 2*lane, 2*lane+1
    float tvx = 0.0f, tvy = 0.0f;
    #pragma unroll
    for (int k = 0; k < LCHK; ++k) {
        const float2 tp = *reinterpret_cast<const float2*>(
            &tpart[((size_t)k * NLBL + c) * D + 2 * lane]);
        tvx += tp.x;
        tvy += tp.y;
    }
    __hip_bfloat16 h0, h1;
    *reinterpret_cast<ushort*>(&h0) = u.x;
    *reinterpret_cast<ushort*>(&h1) = u.y;
    float dot = __bfloat162float(h0) * tvx + __bfloat162float(h1) * tvy;
    #pragma unroll
    for (int m = 1; m < 64; m <<= 1) dot += __shfl_xor(dot, m);
    // 64 Z-partials, one per lane
    float zs = P[(size_t)lane * N + row];
    #pragma unroll
    for (int m = 1; m < 64; m <<= 1) zs += __shfl_xor(zs, m);
    // label count: lanes 0..7 load the 8 chunk counts, 3-step shuffle sum
    float cf = (lane < LCHK) ? (float)cpart[lane * NLBL + c] : 0.0f;
    cf += __shfl_xor(cf, 1);
    cf += __shfl_xor(cf, 2);
    cf += __shfl_xor(cf, 4);
    if (lane == 0) {
        const float di = dii[row];
        const float zc = zs - EXP2(fmaf(di, K1F, K0F));   // remove self term
        const float cn = cf - 1.0f;                       // exclude self
        const float S  = dot - di;                        // exclude self
        const float denom = fmaxf(cn, 1.0f);
        const float lse   = 10.0f + logf(zc);
        out[row] = -(10.0f * S) / denom + (cn > 0.5f ? lse : 0.0f);
    }
}

extern "C" void kernel_launch(void* const* d_in, const int* in_sizes, int n_in,
                              void* d_out, int out_size, void* d_ws, size_t ws_size,
                              hipStream_t stream) {
    const float* z = (const float*)d_in[0];
    const int*   y = (const int*)d_in[1];
    float* out = (float*)d_out;

    // ws layout (~4.7 MB)
    ushort* zn    = (ushort*)d_ws;                                  // 2 MB
    float*  dii   = (float*)((char*)d_ws + (size_t)N * D * 2);      // 32 KB
    float*  tpart = dii + N;                                        // 409.6 KB
    int*    cpart = (int*)(tpart + (size_t)LCHK * NLBL * D);        // 3.2 KB
    float*  P     = (float*)((char*)cpart + 4096);                  // 2 MB (64 x N)

    znorm_kernel<<<N / 4, 256, 0, stream>>>(z, zn, dii);
    labelsum_kernel<<<NLBL * LCHK, 256, 0, stream>>>(zn, y, tpart, cpart);
    supcon_main<<<NSTRIP, 256, 0, stream>>>(zn, P);
    supcon_finalize<<<N / 4, 256, 0, stream>>>(zn, y, P, dii, tpart, cpart, out);
}